// Round 3
// baseline (40.748 us; speedup 1.0000x reference)
//
#include <hip/hip_runtime.h>

// LIF current encoder (norse lif_current_encoder), unrolled 32 steps.
//   v' = v + 0.1f*(x - v);  z = (v' >= 1);  v' = z ? 0 : v'
// Output: zs[t][i] -> out[t*N + i], float32. Write-BW-bound (201 MB writes).
// Stores are nontemporal (write-once, never re-read -> bypass cache alloc);
// fill kernel shows the pure-write path sustains ~6.9 TB/s.
// Note: __builtin_nontemporal_store needs a clang native vector type, not
// HIP_vector_type -> use ext_vector_type(4) float.

#define SEQ_LEN 32

typedef float f32x4 __attribute__((ext_vector_type(4)));

__global__ __launch_bounds__(256) void lif_encode_kernel(
    const f32x4* __restrict__ X, f32x4* __restrict__ out, int n4)
{
    int i = blockIdx.x * blockDim.x + threadIdx.x;
    if (i >= n4) return;

    f32x4 x = X[i];
    float vx = 0.0f, vy = 0.0f, vz = 0.0f, vw = 0.0f;

    f32x4* p = out + i;

#pragma unroll
    for (int t = 0; t < SEQ_LEN; ++t) {
        vx = vx + 0.1f * (x.x - vx);
        vy = vy + 0.1f * (x.y - vy);
        vz = vz + 0.1f * (x.z - vz);
        vw = vw + 0.1f * (x.w - vw);

        f32x4 z;
        z.x = (vx >= 1.0f) ? 1.0f : 0.0f;
        z.y = (vy >= 1.0f) ? 1.0f : 0.0f;
        z.z = (vz >= 1.0f) ? 1.0f : 0.0f;
        z.w = (vw >= 1.0f) ? 1.0f : 0.0f;

        vx = (vx >= 1.0f) ? 0.0f : vx;
        vy = (vy >= 1.0f) ? 0.0f : vy;
        vz = (vz >= 1.0f) ? 0.0f : vz;
        vw = (vw >= 1.0f) ? 0.0f : vw;

        __builtin_nontemporal_store(z, p);
        p += n4;
    }
}

extern "C" void kernel_launch(void* const* d_in, const int* in_sizes, int n_in,
                              void* d_out, int out_size, void* d_ws, size_t ws_size,
                              hipStream_t stream) {
    const f32x4* X = (const f32x4*)d_in[0];
    f32x4* out = (f32x4*)d_out;

    int n = in_sizes[0];      // 1,572,864 (divisible by 4)
    int n4 = n / 4;           // 393,216 float4 elements per timestep

    const int block = 256;
    const int grid = (n4 + block - 1) / block;   // 1536 blocks
    lif_encode_kernel<<<grid, block, 0, stream>>>(X, out, n4);
}

// Round 4
// 32.972 us; speedup vs baseline: 1.2358x; 1.2358x over previous
//
#include <hip/hip_runtime.h>

// LIF current encoder (norse lif_current_encoder), 32 steps.
//   v' = v + 0.1f*(x - v);  z = (v' >= 1);  v' = z ? 0 : v'
// Output: zs[t][i] -> out[t*N + i], float32. Write-BW-bound (201 MB writes).
// R3 lesson: nontemporal stores REGRESS (40.7 vs 35.8 us) -> normal stores.
// This round: time-split. grid.y=4 chunks of 8 timesteps; each thread redoes
// the cheap warm-up recurrence (uniform trip count, no divergence) then emits
// 8 stores. 4x wave parallelism, 8-deep (not 32-deep) per-thread store chain.

#define T_TOTAL 32
#define T_CHUNK 8

typedef float f32x4 __attribute__((ext_vector_type(4)));

__global__ __launch_bounds__(256) void lif_encode_kernel(
    const f32x4* __restrict__ X, f32x4* __restrict__ out, int n4)
{
    int j = blockIdx.x * blockDim.x + threadIdx.x;
    if (j >= n4) return;

    const int t0 = blockIdx.y * T_CHUNK;   // uniform per block

    f32x4 x = X[j];
    float vx = 0.0f, vy = 0.0f, vz = 0.0f, vw = 0.0f;

    // Warm-up: advance the recurrence to t0 (no stores). Same FP ops in the
    // same order as the full iteration -> bit-identical v at chunk start.
    for (int t = 0; t < t0; ++t) {
        vx = vx + 0.1f * (x.x - vx);
        vy = vy + 0.1f * (x.y - vy);
        vz = vz + 0.1f * (x.z - vz);
        vw = vw + 0.1f * (x.w - vw);
        vx = (vx >= 1.0f) ? 0.0f : vx;
        vy = (vy >= 1.0f) ? 0.0f : vy;
        vz = (vz >= 1.0f) ? 0.0f : vz;
        vw = (vw >= 1.0f) ? 0.0f : vw;
    }

    f32x4* p = out + (size_t)t0 * (size_t)n4 + (size_t)j;

#pragma unroll
    for (int t = 0; t < T_CHUNK; ++t) {
        vx = vx + 0.1f * (x.x - vx);
        vy = vy + 0.1f * (x.y - vy);
        vz = vz + 0.1f * (x.z - vz);
        vw = vw + 0.1f * (x.w - vw);

        f32x4 z;
        z.x = (vx >= 1.0f) ? 1.0f : 0.0f;
        z.y = (vy >= 1.0f) ? 1.0f : 0.0f;
        z.z = (vz >= 1.0f) ? 1.0f : 0.0f;
        z.w = (vw >= 1.0f) ? 1.0f : 0.0f;

        vx = (vx >= 1.0f) ? 0.0f : vx;
        vy = (vy >= 1.0f) ? 0.0f : vy;
        vz = (vz >= 1.0f) ? 0.0f : vz;
        vw = (vw >= 1.0f) ? 0.0f : vw;

        *p = z;
        p += n4;
    }
}

extern "C" void kernel_launch(void* const* d_in, const int* in_sizes, int n_in,
                              void* d_out, int out_size, void* d_ws, size_t ws_size,
                              hipStream_t stream) {
    const f32x4* X = (const f32x4*)d_in[0];
    f32x4* out = (f32x4*)d_out;

    int n = in_sizes[0];      // 1,572,864 (divisible by 4)
    int n4 = n / 4;           // 393,216 float4 elements per timestep

    const int block = 256;
    dim3 grid((n4 + block - 1) / block, T_TOTAL / T_CHUNK);  // 1536 x 4
    lif_encode_kernel<<<grid, block, 0, stream>>>(X, out, n4);
}